// Round 11
// baseline (329.603 us; speedup 1.0000x reference)
//
#include <hip/hip_runtime.h>
#include <math.h>

#define BB 2
#define DD 16
#define HH 64
#define WW 64
#define WF 33   // WW/2+1
#define CC 256

typedef __attribute__((ext_vector_type(8))) short bf16x8;
typedef __attribute__((ext_vector_type(4))) float f32x4;
typedef __attribute__((ext_vector_type(4))) unsigned int u32x4;

__device__ __forceinline__ unsigned short f2bf(float f) {
    unsigned u = __builtin_bit_cast(unsigned int, f);
    u += 0x7fffu + ((u >> 16) & 1u);   // round-to-nearest-even
    return (unsigned short)(u >> 16);
}

__device__ __forceinline__ bf16x8 bneg(bf16x8 a) {
    u32x4 u = __builtin_bit_cast(u32x4, a);
    u = u ^ 0x80008000u;               // flip both packed bf16 signs
    return __builtin_bit_cast(bf16x8, u);
}

__device__ __forceinline__ float2 cmul(float2 a, float2 b) {
    return make_float2(a.x * b.x - a.y * b.y, a.x * b.y + a.y * b.x);
}

// Fully-unrolled in-register radix-2 DIT complex FFT. INV=true => e^{+i}, unnormalized.
template <int N, bool INV>
__device__ __forceinline__ void cfft(float2* v) {
    constexpr int L = (N == 64) ? 6 : (N == 32) ? 5 : (N == 16) ? 4 : 0;
    static_assert(L > 0, "unsupported N");
#pragma unroll
    for (int i = 0; i < N; ++i) {
        int j = 0;
#pragma unroll
        for (int bpos = 0; bpos < L; ++bpos) j |= ((i >> bpos) & 1) << (L - 1 - bpos);
        if (j > i) { float2 t = v[i]; v[i] = v[j]; v[j] = t; }
    }
#pragma unroll
    for (int s = 1; s <= L; ++s) {
        const int m = 1 << s;
#pragma unroll
        for (int k = 0; k < N; k += m) {
#pragma unroll
            for (int j = 0; j < m / 2; ++j) {
                float ang = (INV ? 2.0f : -2.0f) * 3.14159265358979323846f * (float)j / (float)m;
                float ss, cc;
                __sincosf(ang, &ss, &cc);
                float2 w = make_float2(cc, ss);
                float2 u = v[k + j];
                float2 t = cmul(w, v[k + j + m / 2]);
                v[k + j]         = make_float2(u.x + t.x, u.y + t.y);
                v[k + j + m / 2] = make_float2(u.x - t.x, u.y - t.y);
            }
        }
    }
}

// Kernel A (r8 form): rfft along W, two real channels packed into one complex FFT-64.
// Thread owns channel pair (2cp, 2cp+1): float2 loads, float4 stores.
// grid (HH/2, D, B); block 256 = 2 h-rows x 128 channel-pairs.
__global__ __launch_bounds__(256) void kA(const float* __restrict__ x, float2* __restrict__ spec) {
    const int t = threadIdx.x;
    const int h = blockIdx.x * 2 + (t >> 7);
    const int d = blockIdx.y, b = blockIdx.z;
    const int cp = t & 127;
    const float2* px = (const float2*)(x + (((size_t)(b * DD + d) * HH + h) * WW) * CC) + cp;
    float2 u[WW];
#pragma unroll
    for (int w = 0; w < WW; ++w) u[w] = px[(size_t)w * (CC / 2)];
    cfft<64, false>(u);
    float2* ps = spec + (((size_t)(b * DD + d) * HH + h) * WF) * CC + 2 * cp;
    const float s = 0.5f / 256.0f;     // ortho scale folded with the 1/2 split factor
#pragma unroll
    for (int k = 0; k < WF; ++k) {
        float2 p = u[k];
        float2 q = u[(64 - k) & 63];
        float4 o;
        o.x = (p.x + q.x) * s;   // A.re  (channel 2cp)
        o.y = (p.y - q.y) * s;   // A.im
        o.z = (p.y + q.y) * s;   // B.re  (channel 2cp+1)
        o.w = (q.x - p.x) * s;   // B.im
        *(float4*)(ps + (size_t)k * CC) = o;
    }
}

// Kernel B/D: complex FFT along H, in-place. grid (WF, D, B).
template <bool INV>
__global__ __launch_bounds__(256) void kH(float2* __restrict__ spec) {
    const int wf = blockIdx.x, d = blockIdx.y, b = blockIdx.z, c = threadIdx.x;
    float2* ps = spec + (((size_t)(b * DD + d) * HH) * WF + wf) * CC + c;
    const size_t sh = (size_t)WF * CC;
    float2 v[HH];
#pragma unroll
    for (int h = 0; h < HH; ++h) v[h] = ps[(size_t)h * sh];
    cfft<64, INV>(v);
#pragma unroll
    for (int h = 0; h < HH; ++h) ps[(size_t)h * sh] = v[h];
}

__device__ __forceinline__ float softshrink(float v) {
    return (v > 0.01f) ? v - 0.01f : ((v < -0.01f) ? v + 0.01f : 0.0f);
}

// Kernel C: FFT-D + MFMA block-MLP + iFFT-D, in-place. grid (WF, H, B), 256 thr = 4 waves.
__global__ __launch_bounds__(256) void kC(float2* __restrict__ spec,
                                          const float* __restrict__ w1, const float* __restrict__ b1,
                                          const float* __restrict__ w2, const float* __restrict__ b2) {
    const int wf = blockIdx.x, h = blockIdx.y, b = blockIdx.z;
    const int c = threadIdx.x;
    const int wv = c >> 6, lane = c & 63;
    const int lrow = lane & 15, lgrp = lane >> 4;

    __shared__ __align__(16) unsigned char smem[32768];

    float2* ps = spec + (((size_t)b * DD * HH + h) * WF + wf) * CC + c;
    const size_t sd = (size_t)HH * WF * CC;

    float b1r_[2][2], b1i_[2][2], b2r_[2][2], b2i_[2][2];
#pragma unroll
    for (int nb = 0; nb < 2; ++nb) {
        const int n = 2 * wv + nb;
#pragma unroll
        for (int t = 0; t < 2; ++t) {
            const int ob = n * 32 + t * 16 + lrow;
            b1r_[nb][t] = b1[ob];  b1i_[nb][t] = b1[256 + ob];
            b2r_[nb][t] = b2[ob];  b2i_[nb][t] = b2[256 + ob];
        }
    }

    bf16x8 Wr[2][2], Wi[2][2];
#pragma unroll
    for (int nb = 0; nb < 2; ++nb) {
        const int n = 2 * wv + nb;
#pragma unroll
        for (int t = 0; t < 2; ++t) {
            const int col = t * 16 + lrow;
#pragma unroll
            for (int j = 0; j < 8; ++j) {
                const int k = lgrp * 8 + j;
                Wr[nb][t][j] = (short)f2bf(w1[n * 1024 + k * 32 + col]);
                Wi[nb][t][j] = (short)f2bf(w1[8192 + n * 1024 + k * 32 + col]);
            }
        }
    }

    float2 v[DD];
#pragma unroll
    for (int d = 0; d < DD; ++d) v[d] = ps[(size_t)d * sd];
    cfft<16, false>(v);

    {
        const int n = c >> 5, in = c & 31;
        unsigned short* Ar = (unsigned short*)smem;
#pragma unroll
        for (int d = 0; d < DD; ++d) {
            Ar[n * 512 + d * 32 + in]        = f2bf(v[d].x);
            Ar[4096 + n * 512 + d * 32 + in] = f2bf(v[d].y);
        }
    }
    __syncthreads();

    const f32x4 zero = {0.f, 0.f, 0.f, 0.f};

#pragma unroll
    for (int nb = 0; nb < 2; ++nb) {
        const int n = 2 * wv + nb;
        const int abase = n * 1024 + lrow * 64 + lgrp * 16;
        bf16x8 xr  = *(const bf16x8*)(smem + abase);
        bf16x8 xi  = *(const bf16x8*)(smem + 8192 + abase);
        bf16x8 nxi = bneg(xi);
        unsigned short* H = (unsigned short*)(smem + 16384);
#pragma unroll
        for (int t = 0; t < 2; ++t) {
            f32x4 rr = __builtin_amdgcn_mfma_f32_16x16x32_bf16(xr, Wr[nb][t], zero, 0, 0, 0);
            rr = __builtin_amdgcn_mfma_f32_16x16x32_bf16(nxi, Wi[nb][t], rr, 0, 0, 0);
            f32x4 ii = __builtin_amdgcn_mfma_f32_16x16x32_bf16(xi, Wr[nb][t], zero, 0, 0, 0);
            ii = __builtin_amdgcn_mfma_f32_16x16x32_bf16(xr, Wi[nb][t], ii, 0, 0, 0);
            const int hcol = n * 512 + (t * 16 + lrow);
#pragma unroll
            for (int r = 0; r < 4; ++r) {
                const int d = lgrp * 4 + r;
                H[hcol + d * 32]        = f2bf(fmaxf(rr[r] + b1r_[nb][t], 0.f));
                H[4096 + hcol + d * 32] = f2bf(fmaxf(ii[r] + b1i_[nb][t], 0.f));
            }
        }
    }
    __syncthreads();

#pragma unroll
    for (int nb = 0; nb < 2; ++nb) {
        const int n = 2 * wv + nb;
#pragma unroll
        for (int t = 0; t < 2; ++t) {
            const int col = t * 16 + lrow;
#pragma unroll
            for (int j = 0; j < 8; ++j) {
                const int k = lgrp * 8 + j;
                Wr[nb][t][j] = (short)f2bf(w2[n * 1024 + k * 32 + col]);
                Wi[nb][t][j] = (short)f2bf(w2[8192 + n * 1024 + k * 32 + col]);
            }
        }
    }

    f32x4 arr[2][2], aii[2][2];
#pragma unroll
    for (int nb = 0; nb < 2; ++nb) {
        const int n = 2 * wv + nb;
        const int hbase = 16384 + n * 1024 + lrow * 64 + lgrp * 16;
        bf16x8 hr  = *(const bf16x8*)(smem + hbase);
        bf16x8 hi  = *(const bf16x8*)(smem + 8192 + hbase);
        bf16x8 nhi = bneg(hi);
#pragma unroll
        for (int t = 0; t < 2; ++t) {
            f32x4 rr = __builtin_amdgcn_mfma_f32_16x16x32_bf16(hr, Wr[nb][t], zero, 0, 0, 0);
            rr = __builtin_amdgcn_mfma_f32_16x16x32_bf16(nhi, Wi[nb][t], rr, 0, 0, 0);
            f32x4 ii = __builtin_amdgcn_mfma_f32_16x16x32_bf16(hi, Wr[nb][t], zero, 0, 0, 0);
            ii = __builtin_amdgcn_mfma_f32_16x16x32_bf16(hr, Wi[nb][t], ii, 0, 0, 0);
            arr[nb][t] = rr;  aii[nb][t] = ii;
        }
    }
    __syncthreads();

    float2* FO = (float2*)smem;
#pragma unroll
    for (int nb = 0; nb < 2; ++nb) {
        const int n = 2 * wv + nb;
#pragma unroll
        for (int t = 0; t < 2; ++t) {
            const int co = n * 32 + t * 16 + lrow;
#pragma unroll
            for (int r = 0; r < 4; ++r) {
                const int d = lgrp * 4 + r;
                FO[d * 256 + co] = make_float2(softshrink(arr[nb][t][r] + b2r_[nb][t]),
                                               softshrink(aii[nb][t][r] + b2i_[nb][t]));
            }
        }
    }
    __syncthreads();

#pragma unroll
    for (int d = 0; d < DD; ++d) v[d] = FO[d * 256 + c];
    cfft<16, true>(v);
#pragma unroll
    for (int d = 0; d < DD; ++d) ps[(size_t)d * sd] = v[d];
}

// Kernel E (paired): irfft along W for TWO channels via ONE complex iFFT-64.
// Z[k] = A[k] + i*B[k] (k<=32, Im of DC/Nyquist dropped per numpy c2r);
// Z[64-m] = conj(A[m]) + i*conj(B[m]). Then Re(ifft)=chan 2cp, Im=chan 2cp+1.
// float4 spec loads (16B/lane), float2 x loads / out stores (8B/lane).
// grid (HH/2, D, B); block 256 = 2 h-rows x 128 channel-pairs.
__global__ __launch_bounds__(256) void kE(const float2* __restrict__ spec, const float* __restrict__ x,
                                          float* __restrict__ out) {
    const int t = threadIdx.x;
    const int h = blockIdx.x * 2 + (t >> 7);
    const int d = blockIdx.y, b = blockIdx.z;
    const int cp = t & 127;
    const float2* ps = spec + (((size_t)(b * DD + d) * HH + h) * WF) * CC + 2 * cp;

    float2 v[WW];
    {   // k = 0: drop Im(A0), Im(B0)
        float4 q = *(const float4*)(ps);
        v[0] = make_float2(q.x, q.z);
    }
    {   // k = 32 (Nyquist): drop imag
        float4 q = *(const float4*)(ps + (size_t)32 * CC);
        v[32] = make_float2(q.x, q.z);
    }
#pragma unroll
    for (int k = 1; k < 32; ++k) {
        float4 q = *(const float4*)(ps + (size_t)k * CC);   // (A.re, A.im, B.re, B.im)
        v[k]      = make_float2(q.x - q.w, q.y + q.z);      // A + iB
        v[64 - k] = make_float2(q.x + q.w, q.z - q.y);      // conj(A) + i*conj(B)
    }
    cfft<64, true>(v);

    const float2* px = (const float2*)(x + (((size_t)(b * DD + d) * HH + h) * WW) * CC) + cp;
    float2* po = (float2*)(out + (((size_t)(b * DD + d) * HH + h) * WW) * CC) + cp;
    const float s = 1.0f / 256.0f;
#pragma unroll
    for (int w = 0; w < WW; ++w) {
        float2 xb = px[(size_t)w * (CC / 2)];
        po[(size_t)w * (CC / 2)] = make_float2(v[w].x * s + xb.x, v[w].y * s + xb.y);
    }
}

extern "C" void kernel_launch(void* const* d_in, const int* in_sizes, int n_in,
                              void* d_out, int out_size, void* d_ws, size_t ws_size,
                              hipStream_t stream) {
    const float* x  = (const float*)d_in[0];
    const float* w1 = (const float*)d_in[1];
    const float* b1 = (const float*)d_in[2];
    const float* w2 = (const float*)d_in[3];
    const float* b2 = (const float*)d_in[4];
    float* out = (float*)d_out;
    float2* spec = (float2*)d_ws;  // [B][D][H][WF][C] complex fp32, 138,412,032 bytes

    dim3 blk(256);
    kA<<<dim3(HH / 2, DD, BB), blk, 0, stream>>>(x, spec);
    kH<false><<<dim3(WF, DD, BB), blk, 0, stream>>>(spec);
    kC<<<dim3(WF, HH, BB), blk, 0, stream>>>(spec, w1, b1, w2, b2);
    kH<true><<<dim3(WF, DD, BB), blk, 0, stream>>>(spec);
    kE<<<dim3(HH / 2, DD, BB), blk, 0, stream>>>(spec, x, out);
}

// Round 12
// 277.272 us; speedup vs baseline: 1.1887x; 1.1887x over previous
//
#include <hip/hip_runtime.h>
#include <math.h>

#define BB 2
#define DD 16
#define HH 64
#define WW 64
#define WF 33   // WW/2+1
#define CC 256

typedef __attribute__((ext_vector_type(8))) short bf16x8;
typedef __attribute__((ext_vector_type(4))) float f32x4;
typedef __attribute__((ext_vector_type(4))) unsigned int u32x4;

__device__ __forceinline__ unsigned short f2bf(float f) {
    unsigned u = __builtin_bit_cast(unsigned int, f);
    u += 0x7fffu + ((u >> 16) & 1u);   // round-to-nearest-even
    return (unsigned short)(u >> 16);
}

__device__ __forceinline__ bf16x8 bneg(bf16x8 a) {
    u32x4 u = __builtin_bit_cast(u32x4, a);
    u = u ^ 0x80008000u;               // flip both packed bf16 signs
    return __builtin_bit_cast(bf16x8, u);
}

__device__ __forceinline__ float2 cmul(float2 a, float2 b) {
    return make_float2(a.x * b.x - a.y * b.y, a.x * b.y + a.y * b.x);
}

// Fully-unrolled in-register radix-2 DIT complex FFT. INV=true => e^{+i}, unnormalized.
template <int N, bool INV>
__device__ __forceinline__ void cfft(float2* v) {
    constexpr int L = (N == 64) ? 6 : (N == 32) ? 5 : (N == 16) ? 4 : 0;
    static_assert(L > 0, "unsupported N");
#pragma unroll
    for (int i = 0; i < N; ++i) {
        int j = 0;
#pragma unroll
        for (int bpos = 0; bpos < L; ++bpos) j |= ((i >> bpos) & 1) << (L - 1 - bpos);
        if (j > i) { float2 t = v[i]; v[i] = v[j]; v[j] = t; }
    }
#pragma unroll
    for (int s = 1; s <= L; ++s) {
        const int m = 1 << s;
#pragma unroll
        for (int k = 0; k < N; k += m) {
#pragma unroll
            for (int j = 0; j < m / 2; ++j) {
                float ang = (INV ? 2.0f : -2.0f) * 3.14159265358979323846f * (float)j / (float)m;
                float ss, cc;
                __sincosf(ang, &ss, &cc);
                float2 w = make_float2(cc, ss);
                float2 u = v[k + j];
                float2 t = cmul(w, v[k + j + m / 2]);
                v[k + j]         = make_float2(u.x + t.x, u.y + t.y);
                v[k + j + m / 2] = make_float2(u.x - t.x, u.y - t.y);
            }
        }
    }
}

// Kernel A (r8 form, best measured): rfft along W, two real channels packed into
// one complex FFT-64. Thread owns channel pair (2cp, 2cp+1): float2 loads,
// float4 stores. grid (HH/2, D, B); block 256 = 2 h-rows x 128 channel-pairs.
__global__ __launch_bounds__(256) void kA(const float* __restrict__ x, float2* __restrict__ spec) {
    const int t = threadIdx.x;
    const int h = blockIdx.x * 2 + (t >> 7);
    const int d = blockIdx.y, b = blockIdx.z;
    const int cp = t & 127;
    const float2* px = (const float2*)(x + (((size_t)(b * DD + d) * HH + h) * WW) * CC) + cp;
    float2 u[WW];
#pragma unroll
    for (int w = 0; w < WW; ++w) u[w] = px[(size_t)w * (CC / 2)];
    cfft<64, false>(u);
    float2* ps = spec + (((size_t)(b * DD + d) * HH + h) * WF) * CC + 2 * cp;
    const float s = 0.5f / 256.0f;     // ortho scale folded with the 1/2 split factor
#pragma unroll
    for (int k = 0; k < WF; ++k) {
        float2 p = u[k];
        float2 q = u[(64 - k) & 63];
        float4 o;
        o.x = (p.x + q.x) * s;   // A.re  (channel 2cp)
        o.y = (p.y - q.y) * s;   // A.im
        o.z = (p.y + q.y) * s;   // B.re  (channel 2cp+1)
        o.w = (q.x - p.x) * s;   // B.im
        *(float4*)(ps + (size_t)k * CC) = o;
    }
}

// Kernel B/D: complex FFT along H, in-place. grid (WF, D, B).
template <bool INV>
__global__ __launch_bounds__(256) void kH(float2* __restrict__ spec) {
    const int wf = blockIdx.x, d = blockIdx.y, b = blockIdx.z, c = threadIdx.x;
    float2* ps = spec + (((size_t)(b * DD + d) * HH) * WF + wf) * CC + c;
    const size_t sh = (size_t)WF * CC;
    float2 v[HH];
#pragma unroll
    for (int h = 0; h < HH; ++h) v[h] = ps[(size_t)h * sh];
    cfft<64, INV>(v);
#pragma unroll
    for (int h = 0; h < HH; ++h) ps[(size_t)h * sh] = v[h];
}

__device__ __forceinline__ float softshrink(float v) {
    return (v > 0.01f) ? v - 0.01f : ((v < -0.01f) ? v + 0.01f : 0.0f);
}

// Kernel C: FFT-D + MFMA block-MLP + iFFT-D, in-place. grid (WF, H, B), 256 thr = 4 waves.
__global__ __launch_bounds__(256) void kC(float2* __restrict__ spec,
                                          const float* __restrict__ w1, const float* __restrict__ b1,
                                          const float* __restrict__ w2, const float* __restrict__ b2) {
    const int wf = blockIdx.x, h = blockIdx.y, b = blockIdx.z;
    const int c = threadIdx.x;
    const int wv = c >> 6, lane = c & 63;
    const int lrow = lane & 15, lgrp = lane >> 4;

    __shared__ __align__(16) unsigned char smem[32768];

    float2* ps = spec + (((size_t)b * DD * HH + h) * WF + wf) * CC + c;
    const size_t sd = (size_t)HH * WF * CC;

    float b1r_[2][2], b1i_[2][2], b2r_[2][2], b2i_[2][2];
#pragma unroll
    for (int nb = 0; nb < 2; ++nb) {
        const int n = 2 * wv + nb;
#pragma unroll
        for (int t = 0; t < 2; ++t) {
            const int ob = n * 32 + t * 16 + lrow;
            b1r_[nb][t] = b1[ob];  b1i_[nb][t] = b1[256 + ob];
            b2r_[nb][t] = b2[ob];  b2i_[nb][t] = b2[256 + ob];
        }
    }

    bf16x8 Wr[2][2], Wi[2][2];
#pragma unroll
    for (int nb = 0; nb < 2; ++nb) {
        const int n = 2 * wv + nb;
#pragma unroll
        for (int t = 0; t < 2; ++t) {
            const int col = t * 16 + lrow;
#pragma unroll
            for (int j = 0; j < 8; ++j) {
                const int k = lgrp * 8 + j;
                Wr[nb][t][j] = (short)f2bf(w1[n * 1024 + k * 32 + col]);
                Wi[nb][t][j] = (short)f2bf(w1[8192 + n * 1024 + k * 32 + col]);
            }
        }
    }

    float2 v[DD];
#pragma unroll
    for (int d = 0; d < DD; ++d) v[d] = ps[(size_t)d * sd];
    cfft<16, false>(v);

    {
        const int n = c >> 5, in = c & 31;
        unsigned short* Ar = (unsigned short*)smem;
#pragma unroll
        for (int d = 0; d < DD; ++d) {
            Ar[n * 512 + d * 32 + in]        = f2bf(v[d].x);
            Ar[4096 + n * 512 + d * 32 + in] = f2bf(v[d].y);
        }
    }
    __syncthreads();

    const f32x4 zero = {0.f, 0.f, 0.f, 0.f};

#pragma unroll
    for (int nb = 0; nb < 2; ++nb) {
        const int n = 2 * wv + nb;
        const int abase = n * 1024 + lrow * 64 + lgrp * 16;
        bf16x8 xr  = *(const bf16x8*)(smem + abase);
        bf16x8 xi  = *(const bf16x8*)(smem + 8192 + abase);
        bf16x8 nxi = bneg(xi);
        unsigned short* H = (unsigned short*)(smem + 16384);
#pragma unroll
        for (int t = 0; t < 2; ++t) {
            f32x4 rr = __builtin_amdgcn_mfma_f32_16x16x32_bf16(xr, Wr[nb][t], zero, 0, 0, 0);
            rr = __builtin_amdgcn_mfma_f32_16x16x32_bf16(nxi, Wi[nb][t], rr, 0, 0, 0);
            f32x4 ii = __builtin_amdgcn_mfma_f32_16x16x32_bf16(xi, Wr[nb][t], zero, 0, 0, 0);
            ii = __builtin_amdgcn_mfma_f32_16x16x32_bf16(xr, Wi[nb][t], ii, 0, 0, 0);
            const int hcol = n * 512 + (t * 16 + lrow);
#pragma unroll
            for (int r = 0; r < 4; ++r) {
                const int d = lgrp * 4 + r;
                H[hcol + d * 32]        = f2bf(fmaxf(rr[r] + b1r_[nb][t], 0.f));
                H[4096 + hcol + d * 32] = f2bf(fmaxf(ii[r] + b1i_[nb][t], 0.f));
            }
        }
    }
    __syncthreads();

#pragma unroll
    for (int nb = 0; nb < 2; ++nb) {
        const int n = 2 * wv + nb;
#pragma unroll
        for (int t = 0; t < 2; ++t) {
            const int col = t * 16 + lrow;
#pragma unroll
            for (int j = 0; j < 8; ++j) {
                const int k = lgrp * 8 + j;
                Wr[nb][t][j] = (short)f2bf(w2[n * 1024 + k * 32 + col]);
                Wi[nb][t][j] = (short)f2bf(w2[8192 + n * 1024 + k * 32 + col]);
            }
        }
    }

    f32x4 arr[2][2], aii[2][2];
#pragma unroll
    for (int nb = 0; nb < 2; ++nb) {
        const int n = 2 * wv + nb;
        const int hbase = 16384 + n * 1024 + lrow * 64 + lgrp * 16;
        bf16x8 hr  = *(const bf16x8*)(smem + hbase);
        bf16x8 hi  = *(const bf16x8*)(smem + 8192 + hbase);
        bf16x8 nhi = bneg(hi);
#pragma unroll
        for (int t = 0; t < 2; ++t) {
            f32x4 rr = __builtin_amdgcn_mfma_f32_16x16x32_bf16(hr, Wr[nb][t], zero, 0, 0, 0);
            rr = __builtin_amdgcn_mfma_f32_16x16x32_bf16(nhi, Wi[nb][t], rr, 0, 0, 0);
            f32x4 ii = __builtin_amdgcn_mfma_f32_16x16x32_bf16(hi, Wr[nb][t], zero, 0, 0, 0);
            ii = __builtin_amdgcn_mfma_f32_16x16x32_bf16(hr, Wi[nb][t], ii, 0, 0, 0);
            arr[nb][t] = rr;  aii[nb][t] = ii;
        }
    }
    __syncthreads();

    float2* FO = (float2*)smem;
#pragma unroll
    for (int nb = 0; nb < 2; ++nb) {
        const int n = 2 * wv + nb;
#pragma unroll
        for (int t = 0; t < 2; ++t) {
            const int co = n * 32 + t * 16 + lrow;
#pragma unroll
            for (int r = 0; r < 4; ++r) {
                const int d = lgrp * 4 + r;
                FO[d * 256 + co] = make_float2(softshrink(arr[nb][t][r] + b2r_[nb][t]),
                                               softshrink(aii[nb][t][r] + b2i_[nb][t]));
            }
        }
    }
    __syncthreads();

#pragma unroll
    for (int d = 0; d < DD; ++d) v[d] = FO[d * 256 + c];
    cfft<16, true>(v);
#pragma unroll
    for (int d = 0; d < DD; ++d) ps[(size_t)d * sd] = v[d];
}

// Kernel E (r3 form, known-good codegen): Hermitian-extend + full inverse
// FFT-64 along W + ortho scale + bias. Real part of the length-64 iFFT is
// exactly numpy's irfft (Im(DC)/Im(Nyq) only affect the discarded imag).
// grid (H, D, B).
__global__ __launch_bounds__(256) void kE(const float2* __restrict__ spec, const float* __restrict__ x,
                                          float* __restrict__ out) {
    const int h = blockIdx.x, d = blockIdx.y, b = blockIdx.z, c = threadIdx.x;
    const float2* ps = spec + (((size_t)(b * DD + d) * HH + h) * WF) * CC + c;
    float2 v[WW];
#pragma unroll
    for (int k = 0; k < WF; ++k) v[k] = ps[(size_t)k * CC];
#pragma unroll
    for (int k = WF; k < WW; ++k) { float2 t = v[WW - k]; v[k] = make_float2(t.x, -t.y); }
    cfft<64, true>(v);
    const size_t xb = (((size_t)(b * DD + d) * HH + h) * WW) * CC + c;
#pragma unroll
    for (int w = 0; w < WW; ++w) {
        out[xb + (size_t)w * CC] = v[w].x * (1.0f / 256.0f) + x[xb + (size_t)w * CC];
    }
}

extern "C" void kernel_launch(void* const* d_in, const int* in_sizes, int n_in,
                              void* d_out, int out_size, void* d_ws, size_t ws_size,
                              hipStream_t stream) {
    const float* x  = (const float*)d_in[0];
    const float* w1 = (const float*)d_in[1];
    const float* b1 = (const float*)d_in[2];
    const float* w2 = (const float*)d_in[3];
    const float* b2 = (const float*)d_in[4];
    float* out = (float*)d_out;
    float2* spec = (float2*)d_ws;  // [B][D][H][WF][C] complex fp32, 138,412,032 bytes

    dim3 blk(256);
    kA<<<dim3(HH / 2, DD, BB), blk, 0, stream>>>(x, spec);
    kH<false><<<dim3(WF, DD, BB), blk, 0, stream>>>(spec);
    kC<<<dim3(WF, HH, BB), blk, 0, stream>>>(spec, w1, b1, w2, b2);
    kH<true><<<dim3(WF, DD, BB), blk, 0, stream>>>(spec);
    kE<<<dim3(HH, DD, BB), blk, 0, stream>>>(spec, x, out);
}